// Round 7
// baseline (184.575 us; speedup 1.0000x reference)
//
#include <hip/hip_runtime.h>

// x (32,256,56,56) f32, cols (64,4) i32. Per (b,g,w,h): among the 4 channels
// cols[g,:], keep only the FIRST max (jnp.argmax tie-break), zero the rest,
// then ReLU. cols covers all 256 channels, so every output elem is written.
constexpr int B  = 32;
constexpr int C  = 256;
constexpr int P  = 56 * 56;          // 3136 elems per channel plane
constexpr int G  = 64;
constexpr int GS = 4;
constexpr int F  = P / 4;            // 784 float4 per plane
constexpr int TOTAL4 = B * G * F;    // 1,605,632 float4-tasks
constexpr int BLOCK  = 256;
constexpr int ITERS  = 8;            // grid-stride iterations per thread
constexpr int GRIDTH = TOTAL4 / ITERS;       // 200,704 threads
constexpr int BLOCKS = GRIDTH / BLOCK;       // 784 blocks (~3/CU)

typedef float fx4 __attribute__((ext_vector_type(4)));

__global__ __launch_bounds__(BLOCK) void cgm_kernel(const float* __restrict__ x,
                                                    const int* __restrict__ cols,
                                                    float* __restrict__ out) {
    int k0 = blockIdx.x * BLOCK + threadIdx.x;   // 0..200703, grid exact

    // GRIDTH = 200704 = 256*F, so across iterations u and g are invariant and
    // only b advances (+4 per iteration): constant address delta.
    int u  = k0 % F;
    int bg = k0 / F;                 // 0..255
    int g  = bg & (G - 1);
    int b0 = bg >> 6;                // 0..3; b = b0 + 4*i

    long off[GS];
#pragma unroll
    for (int s = 0; s < GS; ++s) {
        int c = cols[g * GS + s];
        off[s] = ((long)b0 * C + c) * (long)P + (long)u * 4;
    }
    const long DELTA = (long)(B / ITERS) * C * P;   // 4 batches of elems

    // 2-stage software pipeline: loads for iter i+1 in flight while iter i
    // computes and stores. All array indices static after unroll.
    fx4 cur[GS], nxt[GS];
#pragma unroll
    for (int s = 0; s < GS; ++s)
        cur[s] = *reinterpret_cast<const fx4*>(x + off[s]);

#pragma unroll
    for (int i = 0; i < ITERS; ++i) {
        if (i + 1 < ITERS) {
#pragma unroll
            for (int s = 0; s < GS; ++s)
                nxt[s] = *reinterpret_cast<const fx4*>(x + off[s] + DELTA);
        }

        // Component-wise argmax, FIRST-max tie-break (strict >), then ReLU.
        fx4 o[GS];
#pragma unroll
        for (int s = 0; s < GS; ++s) o[s] = (fx4)0.0f;
#pragma unroll
        for (int j = 0; j < 4; ++j) {
            int   bi   = 0;
            float best = cur[0][j];
#pragma unroll
            for (int s = 1; s < GS; ++s) {
                if (cur[s][j] > best) { best = cur[s][j]; bi = s; }
            }
            float r = best > 0.0f ? best : 0.0f;
#pragma unroll
            for (int s = 0; s < GS; ++s) {
                if (s == bi) o[s][j] = r;
            }
        }

#pragma unroll
        for (int s = 0; s < GS; ++s)
            *reinterpret_cast<fx4*>(out + off[s]) = o[s];

#pragma unroll
        for (int s = 0; s < GS; ++s) {
            off[s] += DELTA;
            cur[s] = nxt[s];
        }
    }
}

extern "C" void kernel_launch(void* const* d_in, const int* in_sizes, int n_in,
                              void* d_out, int out_size, void* d_ws, size_t ws_size,
                              hipStream_t stream) {
    const float* x    = (const float*)d_in[0];
    const int*   cols = (const int*)d_in[1];
    float*       out  = (float*)d_out;

    cgm_kernel<<<dim3(BLOCKS), dim3(BLOCK), 0, stream>>>(x, cols, out);
}